// Round 3
// baseline (564.079 us; speedup 1.0000x reference)
//
#include <hip/hip_runtime.h>
#include <cstddef>
#include <cstdint>

typedef unsigned short ushort_t;
typedef unsigned int uint_t;
typedef __attribute__((ext_vector_type(8))) short short8;
typedef __attribute__((ext_vector_type(4))) float f32x4;

#define EDIM 1024
#define NHEAD 16
#define HDIM 64
#define NB 4
#define LQ 512
#define SK 1024
#define BHD 64

__device__ __forceinline__ ushort_t f2b(float f) {
    uint_t u = __float_as_uint(f);
    return (ushort_t)((u + 0x7fffu + ((u >> 16) & 1u)) >> 16);
}
__device__ __forceinline__ float b2f(ushort_t b) {
    return __uint_as_float(((uint_t)b) << 16);
}

__device__ __forceinline__ void gload_lds16(const void* g, void* l) {
    __builtin_amdgcn_global_load_lds((const __attribute__((address_space(1))) void*)g,
                                     (__attribute__((address_space(3))) void*)l, 16, 0, 0);
}

// ============ mega projection GEMM: all 5 jobs in one balanced launch ======
// blocks 0..255:    K1 merged 3-product split precision -> K1f fp32 head-split
// blocks 256..511:  K2 merged 3-product                 -> K2f fp32 head-split
// blocks 512..767:  V1 (1-pass)                 -> V1b bf16 head-split
// blocks 768..1023: V2 (1-pass)                 -> V2b bf16 head-split
// blocks 1024..1407: QG (1-pass): q -> Qb bf16 head-split *0.125;
//                    g1/g2 -> G1b/G2b bf16 sigmoid flat
// XCD-aware tile remap: each XCD owns a contiguous row-stripe (K/V) or
// col-stripe (QG) so the streamed operand lives in one XCD's L2.
struct MegaArgs {
    const ushort_t *qx, *m1h, *m1l, *m2h, *m2l;
    const ushort_t *Wqg, *Wkv1, *Wkv2, *Wk1l, *Wk2l;
    const float *q_b, *k1_b, *k2_b, *v1_b, *v2_b, *g1_b, *g2_b;
    float *K1f, *K2f;
    ushort_t *V1b, *V2b, *Qb, *G1b, *G2b;
};

__global__ __launch_bounds__(256, 2)
void mega_gemm(MegaArgs a)
{
    __shared__ ushort_t As[128 * 64];
    __shared__ ushort_t Bs[128 * 64];
    const int tid = threadIdx.x;
    const int wave = tid >> 6, lane = tid & 63;
    const int ln = lane & 15, lq = lane >> 4;
    const int wm = wave & 1, wn = wave >> 1;
    const int mrl = lane >> 3;               // row within each 8-row staging group
    const int lswz = (lane & 7) ^ mrl;       // logical slot this lane stages

    const int id = blockIdx.x;
    f32x4 zero = {0.f, 0.f, 0.f, 0.f};

    if (id < 512) {
        // ===== merged split-precision K path: 3 products per 32-k step =====
        const int kind = id >> 8;
        const int t = id & 255;
        const int u = t >> 3;
        const int col0 = (u >> 2) * 128;                 // 8 col-panels
        const int row0 = ((t & 7) * 4 + (u & 3)) * 128;  // XCD owns 4-row stripe
        const ushort_t* Ah  = kind ? a.m2h : a.m1h;
        const ushort_t* Alo = kind ? a.m2l : a.m1l;
        const ushort_t* Bh  = kind ? a.Wkv2 : a.Wkv1;
        const ushort_t* Blo = kind ? a.Wk2l : a.Wk1l;
        const float* bias = kind ? a.k2_b : a.k1_b;

        f32x4 acc[4][4];
#pragma unroll
        for (int i = 0; i < 4; ++i)
#pragma unroll
            for (int j = 0; j < 4; ++j) acc[i][j] = zero;

        const int ksub = (lswz & 3) * 8;                 // k offset within 32-chunk
        const ushort_t* Asrc = (lswz & 4) ? Alo : Ah;    // per-lane hi/lo select
        const ushort_t* Bsrc = (lswz & 4) ? Blo : Bh;

        for (int kk = 0; kk < 1024; kk += 32) {
            __syncthreads();
#pragma unroll
            for (int j = 0; j < 4; ++j) {
                const int mr = (wave * 4 + j) * 8 + mrl;
                gload_lds16(Asrc + (size_t)(row0 + mr) * 1024 + kk + ksub,
                            (void*)(As + (wave * 4 + j) * 512));
                gload_lds16(Bsrc + (size_t)(col0 + mr) * 1024 + kk + ksub,
                            (void*)(Bs + (wave * 4 + j) * 512));
            }
            __syncthreads();
            short8 ah[4], alv[4], bh[4], blv[4];
#pragma unroll
            for (int i = 0; i < 4; ++i) {
                const int ml = wm * 64 + i * 16 + ln;
                const int pa = (lq ^ (ml & 7)) * 8;      // physical hi slot
                ah[i]  = *(const short8*)(As + ml * 64 + pa);
                alv[i] = *(const short8*)(As + ml * 64 + (pa ^ 32)); // lo = hi^4 slots
                const int nl = wn * 64 + i * 16 + ln;
                const int pb = (lq ^ (nl & 7)) * 8;
                bh[i]  = *(const short8*)(Bs + nl * 64 + pb);
                blv[i] = *(const short8*)(Bs + nl * 64 + (pb ^ 32));
            }
#pragma unroll
            for (int i = 0; i < 4; ++i)
#pragma unroll
                for (int j = 0; j < 4; ++j)
                    acc[i][j] = __builtin_amdgcn_mfma_f32_16x16x32_bf16(ah[i], bh[j], acc[i][j], 0, 0, 0);
#pragma unroll
            for (int i = 0; i < 4; ++i)
#pragma unroll
                for (int j = 0; j < 4; ++j)
                    acc[i][j] = __builtin_amdgcn_mfma_f32_16x16x32_bf16(ah[i], blv[j], acc[i][j], 0, 0, 0);
#pragma unroll
            for (int i = 0; i < 4; ++i)
#pragma unroll
                for (int j = 0; j < 4; ++j)
                    acc[i][j] = __builtin_amdgcn_mfma_f32_16x16x32_bf16(alv[i], bh[j], acc[i][j], 0, 0, 0);
        }

        float* Y = kind ? a.K2f : a.K1f;
#pragma unroll
        for (int i = 0; i < 4; ++i) {
#pragma unroll
            for (int r = 0; r < 4; ++r) {
                const int row = row0 + wm * 64 + i * 16 + lq * 4 + r;
#pragma unroll
                for (int j = 0; j < 4; ++j) {
                    const int col = col0 + wn * 64 + j * 16 + ln;
                    const float v = acc[i][j][r] + bias[col];
                    const int s = row >> 2, b = row & 3, h = col >> 6, d = col & 63;
                    Y[(((size_t)(b * 16 + h)) * 1024 + s) * 64 + d] = v;
                }
            }
        }
        return;
    }

    // ===================== V / QG single-pass path =====================
    int kind, row0, col0;
    const ushort_t *A, *B;
    const float* bias;
    if (id < 1024) {
        int t = id - 512; kind = 2 + (t >> 8); t &= 255;
        const int u = t >> 3;
        col0 = (u >> 2) * 128;
        row0 = ((t & 7) * 4 + (u & 3)) * 128;           // XCD row-stripe
        A = (kind == 2) ? a.m1h : a.m2h;
        B = ((kind == 2) ? a.Wkv1 : a.Wkv2) + (size_t)1024 * 1024;
        bias = (kind == 2) ? a.v1_b : a.v2_b;
    } else {
        const int t = id - 1024; kind = 4;
        const int u = t >> 3;
        const int c = (t & 7) * 3 + (u >> 4);           // XCD owns 3 col-panels
        const int rr = u & 15;
        col0 = c * 128; row0 = rr * 128;
        A = a.qx; B = a.Wqg;
        const int seg = c >> 3;
        bias = (seg == 0) ? a.q_b : ((seg == 1) ? a.g1_b : a.g2_b);
    }

    f32x4 acc[4][4];
#pragma unroll
    for (int i = 0; i < 4; ++i)
#pragma unroll
        for (int j = 0; j < 4; ++j) acc[i][j] = zero;

    for (int kk = 0; kk < 1024; kk += 64) {
        __syncthreads();
#pragma unroll
        for (int j = 0; j < 4; ++j) {
            const int mr = (wave * 4 + j) * 8 + mrl;
            gload_lds16(A + (size_t)(row0 + mr) * 1024 + kk + lswz * 8,
                        (void*)(As + (wave * 4 + j) * 512));
            gload_lds16(B + (size_t)(col0 + mr) * 1024 + kk + lswz * 8,
                        (void*)(Bs + (wave * 4 + j) * 512));
        }
        __syncthreads();
#pragma unroll
        for (int sub = 0; sub < 2; ++sub) {
            short8 af[4], bfv[4];
#pragma unroll
            for (int i = 0; i < 4; ++i) {
                const int ml = wm * 64 + i * 16 + ln;
                af[i] = *(const short8*)(As + ml * 64 + (((sub * 4 + lq) ^ (ml & 7)) * 8));
                const int nl = wn * 64 + i * 16 + ln;
                bfv[i] = *(const short8*)(Bs + nl * 64 + (((sub * 4 + lq) ^ (nl & 7)) * 8));
            }
#pragma unroll
            for (int i = 0; i < 4; ++i)
#pragma unroll
                for (int j = 0; j < 4; ++j)
                    acc[i][j] = __builtin_amdgcn_mfma_f32_16x16x32_bf16(af[i], bfv[j], acc[i][j], 0, 0, 0);
        }
    }

#pragma unroll
    for (int i = 0; i < 4; ++i) {
#pragma unroll
        for (int r = 0; r < 4; ++r) {
            const int row = row0 + wm * 64 + i * 16 + lq * 4 + r;
#pragma unroll
            for (int j = 0; j < 4; ++j) {
                const int col = col0 + wn * 64 + j * 16 + ln;
                const int lc = col & 1023;
                float v = acc[i][j][r] + bias[lc];
                if (kind <= 3) {            // V bf16 head-split
                    const int s = row >> 2, b = row & 3, h = lc >> 6, d = lc & 63;
                    ushort_t* Y = (kind == 2) ? a.V1b : a.V2b;
                    Y[(((size_t)(b * 16 + h)) * 1024 + s) * 64 + d] = f2b(v);
                } else {
                    const int seg = col >> 10;
                    if (seg == 0) {         // Q bf16 head-split (L=512), *scale
                        v *= 0.125f;
                        const int s = row >> 2, b = row & 3, h = lc >> 6, d = lc & 63;
                        a.Qb[(((size_t)(b * 16 + h)) * 512 + s) * 64 + d] = f2b(v);
                    } else {                // gates bf16 sigmoid flat
                        v = 1.0f / (1.0f + __expf(-v));
                        ushort_t* Y = (seg == 1) ? a.G1b : a.G2b;
                        Y[(size_t)row * 1024 + lc] = f2b(v);
                    }
                }
            }
        }
    }
}

// =============== fused input/weight casts (one launch) ===============
struct CastArgs {
    const float* q; const float* m1; const float* m2;
    ushort_t* qx; ushort_t* m1h; ushort_t* m1l; ushort_t* m2h; ushort_t* m2l;
    const float* wsrc[8];
    ushort_t* whi[8];
    ushort_t* wlo[8];
};

__global__ __launch_bounds__(256)
void casts_kernel(CastArgs a)
{
    __shared__ float T[64][65];
    const int id = blockIdx.x;
    const int tid = threadIdx.x;
    if (id < 1024) {                       // query cast
        const size_t i = ((size_t)id * 256 + tid) * 8;
        float4 x = *(const float4*)(a.q + i);
        float4 y = *(const float4*)(a.q + i + 4);
        ushort_t o[8] = {f2b(x.x), f2b(x.y), f2b(x.z), f2b(x.w), f2b(y.x), f2b(y.y), f2b(y.z), f2b(y.w)};
        *(uint4*)( (void*)(a.qx + i) ) = *(const uint4*)o;
    } else if (id < 5120) {                // mod hi/lo split casts
        const int t = id - 1024;
        const int which = t >> 11;
        const float* x = which ? a.m2 : a.m1;
        ushort_t* yh = which ? a.m2h : a.m1h;
        ushort_t* yl = which ? a.m2l : a.m1l;
        const size_t i = ((size_t)(t & 2047) * 256 + tid) * 8;
        float v[8];
        *(float4*)v = *(const float4*)(x + i);
        *(float4*)(v + 4) = *(const float4*)(x + i + 4);
        ushort_t oh[8], ol[8];
#pragma unroll
        for (int k = 0; k < 8; ++k) {
            oh[k] = f2b(v[k]);
            ol[k] = f2b(v[k] - b2f(oh[k]));
        }
        *(uint4*)( (void*)(yh + i) ) = *(const uint4*)oh;
        *(uint4*)( (void*)(yl + i) ) = *(const uint4*)ol;
    } else {                               // weight transpose+cast
        const int t = id - 5120;
        const int z = t >> 8, x = t & 15, y = (t >> 4) & 15;
        const float* W = a.wsrc[z];
        ushort_t* Th = a.whi[z];
        ushort_t* Tl = a.wlo[z];
        const int k0 = x * 64, n0 = y * 64;
        const int r = tid >> 2, cg = (tid & 3) * 16;
#pragma unroll
        for (int u = 0; u < 4; ++u) {
            float4 v = *(const float4*)(W + (size_t)(k0 + r) * 1024 + n0 + cg + u * 4);
            T[r][cg + u * 4 + 0] = v.x; T[r][cg + u * 4 + 1] = v.y;
            T[r][cg + u * 4 + 2] = v.z; T[r][cg + u * 4 + 3] = v.w;
        }
        __syncthreads();
        ushort_t oh[16], ol[16];
#pragma unroll
        for (int u = 0; u < 16; ++u) {
            float v = T[cg + u][r];
            oh[u] = f2b(v);
            ol[u] = f2b(v - b2f(oh[u]));
        }
        ushort_t* dh = Th + (size_t)(n0 + r) * 1024 + k0 + cg;
        *(uint4*)( (void*)dh ) = *(const uint4*)oh;
        *(uint4*)( (void*)(dh + 8) ) = *(const uint4*)(oh + 8);
        if (Tl) {
            ushort_t* dl = Tl + (size_t)(n0 + r) * 1024 + k0 + cg;
            *(uint4*)( (void*)dl ) = *(const uint4*)ol;
            *(uint4*)( (void*)(dl + 8) ) = *(const uint4*)(ol + 8);
        }
    }
}

// ====== fused prep: K norms+cast, Q norms, V transpose (one launch) ======
// K-norm branch also precomputes va2 = 2*va and gg = vv*aa - va^2 so the
// fused attention kernel's det math is a 7-op fma chain.
__global__ __launch_bounds__(256)
void prep_kernel(const float* __restrict__ K1f, const float* __restrict__ K2f,
                 ushort_t* __restrict__ K1b, ushort_t* __restrict__ K2b,
                 float* __restrict__ vv, float* __restrict__ aa,
                 float* __restrict__ va2, float* __restrict__ gg,
                 const ushort_t* __restrict__ Qb, float* __restrict__ ll,
                 const ushort_t* __restrict__ V1b, const ushort_t* __restrict__ V2b,
                 ushort_t* __restrict__ V1t, ushort_t* __restrict__ V2t)
{
    __shared__ float T[64][65];
    const int id = blockIdx.x;
    const int tid = threadIdx.x;
    const int wave = tid >> 6, lane = tid & 63;
    if (id < 16384) {                      // K norms (fp32) + bf16 cast
        const int row = id * 4 + wave;
        const float x1 = K1f[(size_t)row * 64 + lane];
        const float x2 = K2f[(size_t)row * 64 + lane];
        K1b[(size_t)row * 64 + lane] = f2b(x1);
        K2b[(size_t)row * 64 + lane] = f2b(x2);
        float s1 = x1 * x1, s2 = x2 * x2, s3 = x1 * x2;
#pragma unroll
        for (int o = 1; o < 64; o <<= 1) {
            s1 += __shfl_xor(s1, o);
            s2 += __shfl_xor(s2, o);
            s3 += __shfl_xor(s3, o);
        }
        if (lane == 0) {
            vv[row] = s1; aa[row] = s2;
            va2[row] = 2.0f * s3;
            gg[row] = s1 * s2 - s3 * s3;
        }
    } else if (id < 24576) {               // Q norms
        const int row = (id - 16384) * 4 + wave;
        const float x = b2f(Qb[(size_t)row * 64 + lane]);
        float s = x * x;
#pragma unroll
        for (int o = 1; o < 64; o <<= 1) s += __shfl_xor(s, o);
        if (lane == 0) ll[row] = s;
    } else {                               // V transpose
        const int t = id - 24576;
        const int z = t >> 10, bh = (t >> 4) & 63, s0 = (t & 15) * 64;
        const ushort_t* S = z ? V2b : V1b;
        ushort_t* D = z ? V2t : V1t;
        const int r = tid >> 2, cg = (tid & 3) * 16;
        ushort_t buf[16];
        const ushort_t* sp = S + ((size_t)bh * 1024 + s0 + r) * 64 + cg;
        *(uint4*)buf = *(const uint4*)sp;
        *(uint4*)(buf + 8) = *(const uint4*)(sp + 8);
#pragma unroll
        for (int u = 0; u < 16; ++u) T[r][cg + u] = b2f(buf[u]);
        __syncthreads();
        ushort_t o[16];
#pragma unroll
        for (int u = 0; u < 16; ++u) o[u] = f2b(T[cg + u][r]);
        ushort_t* d = D + ((size_t)bh * 64 + r) * 1024 + s0 + cg;
        *(uint4*)( (void*)d ) = *(const uint4*)o;
        *(uint4*)( (void*)(d + 8) ) = *(const uint4*)(o + 8);
    }
}

// ====== fused scores + softmax: SINGLE pass, register-resident P' ==========
// Block = (bh, 64 q-rows) x full S=1024. For each 128-col s-tile: MFMA QK,
// det math, tile max; store P' = exp(lgt - mn_tile) packed bf16 in VGPRs
// (pp[8][8][2], statically indexed) and remember mn per tile (mt[8][4]).
// After the loop the final max/sum are known; write-out is unpack * c + f2b
// where c[t][r] = exp(mt - m_final) * inv. No recompute pass.
__global__ __launch_bounds__(256, 2)
void attn_fused(const ushort_t* __restrict__ Qb, const ushort_t* __restrict__ K1b,
                const ushort_t* __restrict__ K2b, const float* __restrict__ ll,
                const float* __restrict__ vv, const float* __restrict__ aa,
                const float* __restrict__ va2, const float* __restrict__ gg,
                ushort_t* __restrict__ attn)
{
    __shared__ ushort_t Qs[64 * 64];
    __shared__ ushort_t K1s[128 * 64];
    __shared__ ushort_t K2s[128 * 64];
    __shared__ float vvS[1024], aaS[1024], vaS[1024], ggS[1024], llS[64];
    const int tid = threadIdx.x;
    const int wave = tid >> 6, lane = tid & 63;
    const int ln = lane & 15, lq = lane >> 4;
    const int mrl = lane >> 3;
    const int cswz = (lane & 7) ^ mrl;
    const float L2E = 1.44269504f;

    const int id = blockIdx.x;
    // bijective XCD map: XCD k owns bh = k*8 .. k*8+7 (all 8 l-blocks local)
    const int bh = (id & 7) * 8 + ((id >> 3) & 7);
    const int l0 = (id >> 6) * 64;

    for (int i = tid; i < 1024; i += 256) {
        vvS[i] = vv[(size_t)bh * 1024 + i];
        aaS[i] = aa[(size_t)bh * 1024 + i];
        vaS[i] = va2[(size_t)bh * 1024 + i];
        ggS[i] = gg[(size_t)bh * 1024 + i];
    }
    if (tid < 64) llS[tid] = ll[(size_t)bh * 512 + l0 + tid];
#pragma unroll
    for (int j = 0; j < 2; ++j) {          // stage Q once (64x64)
        const int mr = (wave * 2 + j) * 8 + mrl;
        gload_lds16(Qb + ((size_t)bh * 512 + l0 + mr) * 64 + cswz * 8,
                    (void*)(Qs + (wave * 2 + j) * 512));
    }

    const int ml = wave * 16 + ln;         // this wave's A-frag row base

    float m_run[4], s_run[4];
#pragma unroll
    for (int r = 0; r < 4; ++r) { m_run[r] = -3.0e38f; s_run[r] = 0.f; }
    uint_t pp[8][8][2];                    // packed bf16 P' (static idx only)
    float mt[8][4];                        // tile-time running max

#pragma unroll
    for (int t = 0; t < 8; ++t) {
        const int s0 = t * 128;
        __syncthreads();
#pragma unroll
        for (int j = 0; j < 4; ++j) {
            const int mr = (wave * 4 + j) * 8 + mrl;
            gload_lds16(K1b + ((size_t)bh * 1024 + s0 + mr) * 64 + cswz * 8,
                        (void*)(K1s + (wave * 4 + j) * 512));
            gload_lds16(K2b + ((size_t)bh * 1024 + s0 + mr) * 64 + cswz * 8,
                        (void*)(K2s + (wave * 4 + j) * 512));
        }
        __syncthreads();
        f32x4 zero = {0.f, 0.f, 0.f, 0.f};
        f32x4 lv[8], la[8];
#pragma unroll
        for (int j = 0; j < 8; ++j) { lv[j] = zero; la[j] = zero; }
#pragma unroll
        for (int sub = 0; sub < 2; ++sub) {
            const short8 qf = *(const short8*)(Qs + ml * 64 + (((sub * 4 + lq) ^ (ml & 7)) * 8));
#pragma unroll
            for (int j = 0; j < 8; ++j) {
                const int nl = j * 16 + ln;
                const short8 k1f = *(const short8*)(K1s + nl * 64 + (((sub * 4 + lq) ^ (nl & 7)) * 8));
                const short8 k2f = *(const short8*)(K2s + nl * 64 + (((sub * 4 + lq) ^ (nl & 7)) * 8));
                lv[j] = __builtin_amdgcn_mfma_f32_16x16x32_bf16(qf, k1f, lv[j], 0, 0, 0);
                la[j] = __builtin_amdgcn_mfma_f32_16x16x32_bf16(qf, k2f, la[j], 0, 0, 0);
            }
        }
        float lgt[8][4];
#pragma unroll
        for (int j = 0; j < 8; ++j) {
            const int c = s0 + j * 16 + ln;
            const float VV = vvS[c], AA = aaS[c], VA2 = vaS[c], GB = ggS[c];
#pragma unroll
            for (int r = 0; r < 4; ++r) {
                const float LL = llS[wave * 16 + lq * 4 + r];
                const float LV = lv[j][r], LA = la[j][r];
                float det = LL * GB;
                det = fmaf(-AA, LV * LV, det);
                det = fmaf(VA2, LV * LA, det);
                det = fmaf(-VV, LA * LA, det);
                det = fmaxf(det, 1e-8f);
                lgt[j][r] = (LV + LA) - 1.5f * sqrtf(det);
            }
        }
        // tile max across the 16 lanes sharing this row group
        float tmax[4];
#pragma unroll
        for (int r = 0; r < 4; ++r) tmax[r] = lgt[0][r];
#pragma unroll
        for (int j = 1; j < 8; ++j)
#pragma unroll
            for (int r = 0; r < 4; ++r) tmax[r] = fmaxf(tmax[r], lgt[j][r]);
#pragma unroll
        for (int r = 0; r < 4; ++r) {
#pragma unroll
            for (int o = 1; o < 16; o <<= 1) tmax[r] = fmaxf(tmax[r], __shfl_xor(tmax[r], o));
        }
        float mn[4], nm[4], ps[4];
#pragma unroll
        for (int r = 0; r < 4; ++r) {
            mn[r] = fmaxf(m_run[r], tmax[r]);
            nm[r] = -mn[r] * L2E;
            ps[r] = 0.f;
        }
#pragma unroll
        for (int j = 0; j < 8; ++j) {
            float p[4];
#pragma unroll
            for (int r = 0; r < 4; ++r) {
                p[r] = exp2f(fmaf(lgt[j][r], L2E, nm[r]));
                ps[r] += p[r];
            }
            pp[t][j][0] = (uint_t)f2b(p[0]) | ((uint_t)f2b(p[1]) << 16);
            pp[t][j][1] = (uint_t)f2b(p[2]) | ((uint_t)f2b(p[3]) << 16);
        }
#pragma unroll
        for (int r = 0; r < 4; ++r) {
            s_run[r] = s_run[r] * __expf(m_run[r] - mn[r]) + ps[r];
            m_run[r] = mn[r];
            mt[t][r] = mn[r];
        }
    }

    float inv[4];
#pragma unroll
    for (int r = 0; r < 4; ++r) {
        float s = s_run[r];
#pragma unroll
        for (int o = 1; o < 16; o <<= 1) s += __shfl_xor(s, o);
        inv[r] = 1.0f / s;
    }

    // ---------------- write-out: unpack * c, f2b, store ----------------
    const size_t rb = (size_t)bh * 512 + l0 + wave * 16 + lq * 4;
#pragma unroll
    for (int t = 0; t < 8; ++t) {
        float c[4];
#pragma unroll
        for (int r = 0; r < 4; ++r) c[r] = __expf(mt[t][r] - m_run[r]) * inv[r];
#pragma unroll
        for (int j = 0; j < 8; ++j) {
            const int col = t * 128 + j * 16 + ln;
            const uint_t u0 = pp[t][j][0], u1 = pp[t][j][1];
            attn[(rb + 0) * 1024 + col] = f2b(__uint_as_float(u0 << 16) * c[0]);
            attn[(rb + 1) * 1024 + col] = f2b(__uint_as_float(u0 & 0xffff0000u) * c[1]);
            attn[(rb + 2) * 1024 + col] = f2b(__uint_as_float(u1 << 16) * c[2]);
            attn[(rb + 3) * 1024 + col] = f2b(__uint_as_float(u1 & 0xffff0000u) * c[3]);
        }
    }
}

// ====== PV (v1,v2) + gating -> tmp bf16 [t][E]; plus head-avg path ========
// flat grid: id < 256 -> PV tile (bh = id>>2, l0 = (id&3)*128);
//            id >= 256 -> avg rows: mean over 16 heads of bf16 P.
__global__ __launch_bounds__(256, 2)
void pv_gate_kernel(const ushort_t* __restrict__ attn, const ushort_t* __restrict__ V1t,
                    const ushort_t* __restrict__ V2t, const ushort_t* __restrict__ G1,
                    const ushort_t* __restrict__ G2, ushort_t* __restrict__ tmpb,
                    float* __restrict__ avg)
{
    __shared__ ushort_t Ps[128 * 64];
    __shared__ ushort_t V1s[64 * 64];
    __shared__ ushort_t V2s[64 * 64];
    const int tid = threadIdx.x;

    if (blockIdx.x >= 256) {               // ---- head-average path ----
        const int t = blockIdx.x - 256;    // 0..2047 = 4 b x 512 l
        const int b = t >> 9, l = t & 511;
        const int c0 = tid * 4;
        float s0_ = 0.f, s1_ = 0.f, s2_ = 0.f, s3_ = 0.f;
#pragma unroll
        for (int h = 0; h < 16; ++h) {
            const ushort_t* p = attn + (((size_t)(b * 16 + h)) * 512 + l) * 1024 + c0;
            ushort_t u[4];
            *(uint2*)u = *(const uint2*)p;
            s0_ += b2f(u[0]); s1_ += b2f(u[1]); s2_ += b2f(u[2]); s3_ += b2f(u[3]);
        }
        float4 o = {s0_ * 0.0625f, s1_ * 0.0625f, s2_ * 0.0625f, s3_ * 0.0625f};
        *(float4*)(avg + ((size_t)(b * 512 + l)) * 1024 + c0) = o;
        return;
    }

    const int wave = tid >> 6, lane = tid & 63;
    const int ln = lane & 15, lq = lane >> 4;
    const int bh = blockIdx.x >> 2;
    const int l0 = (blockIdx.x & 3) * 128;
    const int cswz = (lane & 7) ^ ((lane >> 3) & 7);
    const int mrl = lane >> 3;
    const int bq = bh >> 4, h = bh & 15;

    f32x4 zero = {0.f, 0.f, 0.f, 0.f};
    f32x4 acc1[2][4], acc2[2][4];
#pragma unroll
    for (int i = 0; i < 2; ++i)
#pragma unroll
        for (int j = 0; j < 4; ++j) { acc1[i][j] = zero; acc2[i][j] = zero; }

    for (int s0 = 0; s0 < 1024; s0 += 64) {
        __syncthreads();
#pragma unroll
        for (int j = 0; j < 4; ++j) {
            const int mr = (wave * 4 + j) * 8 + mrl;
            gload_lds16(attn + ((size_t)bh * 512 + l0 + mr) * 1024 + s0 + cswz * 8,
                        (void*)(Ps + (wave * 4 + j) * 512));
        }
#pragma unroll
        for (int j = 0; j < 2; ++j) {
            const int mv = (wave * 2 + j) * 8 + mrl;
            gload_lds16(V1t + ((size_t)bh * 64 + mv) * 1024 + s0 + cswz * 8,
                        (void*)(V1s + (wave * 2 + j) * 512));
            gload_lds16(V2t + ((size_t)bh * 64 + mv) * 1024 + s0 + cswz * 8,
                        (void*)(V2s + (wave * 2 + j) * 512));
        }
        __syncthreads();
#pragma unroll
        for (int sub = 0; sub < 2; ++sub) {
            short8 af[2], b1f[4], b2f_[4];
#pragma unroll
            for (int i = 0; i < 2; ++i) {
                const int ml = wave * 32 + i * 16 + ln;
                af[i] = *(const short8*)(Ps + ml * 64 + (((sub * 4 + lq) ^ (ml & 7)) * 8));
            }
#pragma unroll
            for (int j = 0; j < 4; ++j) {
                const int nl = j * 16 + ln;
                b1f[j] = *(const short8*)(V1s + nl * 64 + (((sub * 4 + lq) ^ (nl & 7)) * 8));
                b2f_[j] = *(const short8*)(V2s + nl * 64 + (((sub * 4 + lq) ^ (nl & 7)) * 8));
            }
#pragma unroll
            for (int i = 0; i < 2; ++i)
#pragma unroll
                for (int j = 0; j < 4; ++j) {
                    acc1[i][j] = __builtin_amdgcn_mfma_f32_16x16x32_bf16(af[i], b1f[j], acc1[i][j], 0, 0, 0);
                    acc2[i][j] = __builtin_amdgcn_mfma_f32_16x16x32_bf16(af[i], b2f_[j], acc2[i][j], 0, 0, 0);
                }
        }
    }

#pragma unroll
    for (int i = 0; i < 2; ++i) {
#pragma unroll
        for (int r = 0; r < 4; ++r) {
            const int l = l0 + wave * 32 + i * 16 + lq * 4 + r;
#pragma unroll
            for (int j = 0; j < 4; ++j) {
                const int d = j * 16 + ln;
                const size_t addr = ((size_t)l * 4 + bq) * 1024 + h * 64 + d;
                const float v = 0.5f * (acc1[i][j][r] * b2f(G1[addr]) + acc2[i][j][r] * b2f(G2[addr]));
                tmpb[addr] = f2b(v);
            }
        }
    }
}

// ============ o-proj: 64x128 tiles, 256 blocks (fixed coverage) ============
__global__ __launch_bounds__(256, 2)
void gemm_o64(const ushort_t* __restrict__ A, const ushort_t* __restrict__ B,
              const float* __restrict__ bias, float* __restrict__ Y)
{
    __shared__ ushort_t As[64 * 64];
    __shared__ ushort_t Bs[128 * 64];
    const int tid = threadIdx.x;
    const int wave = tid >> 6, lane = tid & 63;
    const int ln = lane & 15, lq = lane >> 4;
    const int row0 = blockIdx.y * 64, col0 = blockIdx.x * 128;
    const int wm = wave & 1, wn = wave >> 1;
    const int cswz = (lane & 7) ^ ((lane >> 3) & 7);
    const int mrl = lane >> 3;

    f32x4 zero = {0.f, 0.f, 0.f, 0.f};
    f32x4 acc[2][4];
#pragma unroll
    for (int i = 0; i < 2; ++i)
#pragma unroll
        for (int j = 0; j < 4; ++j) acc[i][j] = zero;

    for (int kk = 0; kk < 1024; kk += 64) {
        __syncthreads();
#pragma unroll
        for (int j = 0; j < 2; ++j) {       // A: 64 rows
            const int mr = (wave * 2 + j) * 8 + mrl;
            gload_lds16(A + (size_t)(row0 + mr) * 1024 + kk + cswz * 8,
                        (void*)(As + (wave * 2 + j) * 512));
        }
#pragma unroll
        for (int j = 0; j < 4; ++j) {       // B: 128 rows
            const int mr = (wave * 4 + j) * 8 + mrl;
            gload_lds16(B + (size_t)(col0 + mr) * 1024 + kk + cswz * 8,
                        (void*)(Bs + (wave * 4 + j) * 512));
        }
        __syncthreads();
#pragma unroll
        for (int sub = 0; sub < 2; ++sub) {
            short8 af[2], bfv[4];
#pragma unroll
            for (int i = 0; i < 2; ++i) {
                const int ml = wm * 32 + i * 16 + ln;
                af[i] = *(const short8*)(As + ml * 64 + (((sub * 4 + lq) ^ (ml & 7)) * 8));
            }
#pragma unroll
            for (int j = 0; j < 4; ++j) {
                const int nl = wn * 64 + j * 16 + ln;
                bfv[j] = *(const short8*)(Bs + nl * 64 + (((sub * 4 + lq) ^ (nl & 7)) * 8));
            }
#pragma unroll
            for (int i = 0; i < 2; ++i)
#pragma unroll
                for (int j = 0; j < 4; ++j)
                    acc[i][j] = __builtin_amdgcn_mfma_f32_16x16x32_bf16(af[i], bfv[j], acc[i][j], 0, 0, 0);
        }
    }

#pragma unroll
    for (int i = 0; i < 2; ++i) {
#pragma unroll
        for (int r = 0; r < 4; ++r) {
            const int row = row0 + wm * 32 + i * 16 + lq * 4 + r;
#pragma unroll
            for (int j = 0; j < 4; ++j) {
                const int col = col0 + wn * 64 + j * 16 + ln;
                Y[(size_t)row * 1024 + col] = acc[i][j][r] + bias[col];
            }
        }
    }
}

// ============================ launch ============================
extern "C" void kernel_launch(void* const* d_in, const int* in_sizes, int n_in,
                              void* d_out, int out_size, void* d_ws, size_t ws_size,
                              hipStream_t stream)
{
    const float* query = (const float*)d_in[0];
    const float* mod1  = (const float*)d_in[1];
    const float* mod2  = (const float*)d_in[2];
    const float* q_w  = (const float*)d_in[3];  const float* q_b  = (const float*)d_in[4];
    const float* k1_w = (const float*)d_in[5];  const float* k1_b = (const float*)d_in[6];
    const float* k2_w = (const float*)d_in[7];  const float* k2_b = (const float*)d_in[8];
    const float* v1_w = (const float*)d_in[9];  const float* v1_b = (const float*)d_in[10];
    const float* v2_w = (const float*)d_in[11]; const float* v2_b = (const float*)d_in[12];
    const float* g1_w = (const float*)d_in[13]; const float* g1_b = (const float*)d_in[14];
    const float* g2_w = (const float*)d_in[15]; const float* g2_b = (const float*)d_in[16];
    const float* o_w  = (const float*)d_in[17]; const float* o_b  = (const float*)d_in[18];
    float* out = (float*)d_out;

    const size_t MB = 1u << 20;
    char* w = (char*)d_ws;
    // persistent region (0..78 MB)
    ushort_t* Wqg  = (ushort_t*)(w + 0 * MB);    // 6 MB [q|g1|g2]^T
    ushort_t* Wkv1 = (ushort_t*)(w + 6 * MB);    // 4 MB [k1|v1]^T
    ushort_t* Wkv2 = (ushort_t*)(w + 10 * MB);   // 4 MB [k2|v2]^T
    ushort_t* Wo   = (ushort_t*)(w + 14 * MB);   // 2 MB
    ushort_t* Wk1l = (ushort_t*)(w + 16 * MB);   // 2 MB
    ushort_t* Wk2l = (ushort_t*)(w + 18 * MB);   // 2 MB
    ushort_t* qx   = (ushort_t*)(w + 20 * MB);   // 4 MB; dead after mega-GEMM
    ushort_t* tmpb = qx;                         // reuse for gated PV output
    ushort_t* Qb   = (ushort_t*)(w + 24 * MB);   // 4 MB (full 64*512*64)
    ushort_t* K1b  = (ushort_t*)(w + 28 * MB);   // 8 MB
    ushort_t* K2b  = (ushort_t*)(w + 36 * MB);   // 8 MB
    ushort_t* V1t  = (ushort_t*)(w + 44 * MB);   // 8 MB
    ushort_t* V2t  = (ushort_t*)(w + 52 * MB);   // 8 MB
    ushort_t* G1b  = (ushort_t*)(w + 60 * MB);   // 4 MB bf16 gates
    ushort_t* G2b  = (ushort_t*)(w + 64 * MB);   // 4 MB
    float* ll  = (float*)(w + 68 * MB);                  // 128 KB
    float* vv  = (float*)(w + 68 * MB + 256 * 1024);     // 256 KB each slot
    float* aa  = (float*)(w + 68 * MB + 512 * 1024);
    float* va2 = (float*)(w + 68 * MB + 768 * 1024);
    float* gg  = (float*)(w + 68 * MB + 1024 * 1024);
    // transient region 78..158 MB; overlays all dead before attn_fused:
    ushort_t* attn = (ushort_t*)(w + 78 * MB);   // 64 MB bf16 [bh][512][1024]
    ushort_t* m1h = (ushort_t*)(w + 78 * MB);    // 8 MB  (dead after mega-GEMM)
    ushort_t* m2h = (ushort_t*)(w + 86 * MB);    // 8 MB
    ushort_t* m1l = (ushort_t*)(w + 94 * MB);    // 8 MB
    ushort_t* m2l = (ushort_t*)(w + 102 * MB);   // 8 MB
    float* K1f = (float*)(w + 110 * MB);         // 16 MB (dead after prep)
    float* K2f = (float*)(w + 126 * MB);         // 16 MB
    ushort_t* V1b = (ushort_t*)(w + 142 * MB);   // 8 MB (dead after prep)
    ushort_t* V2b = (ushort_t*)(w + 150 * MB);   // 8 MB

    // 1) fused casts
    CastArgs ca;
    ca.q = query; ca.m1 = mod1; ca.m2 = mod2;
    ca.qx = qx; ca.m1h = m1h; ca.m1l = m1l; ca.m2h = m2h; ca.m2l = m2l;
    const float* srcs[8] = {q_w, g1_w, g2_w, k1_w, v1_w, k2_w, v2_w, o_w};
    ushort_t* his[8] = {Wqg, Wqg + (size_t)1024 * 1024, Wqg + (size_t)2048 * 1024,
                        Wkv1, Wkv1 + (size_t)1024 * 1024, Wkv2, Wkv2 + (size_t)1024 * 1024, Wo};
    ushort_t* los[8] = {nullptr, nullptr, nullptr, Wk1l, nullptr, Wk2l, nullptr, nullptr};
    for (int i = 0; i < 8; ++i) { ca.wsrc[i] = srcs[i]; ca.whi[i] = his[i]; ca.wlo[i] = los[i]; }
    casts_kernel<<<7168, 256, 0, stream>>>(ca);

    // 2) all projections, one balanced launch
    MegaArgs ma;
    ma.qx = qx; ma.m1h = m1h; ma.m1l = m1l; ma.m2h = m2h; ma.m2l = m2l;
    ma.Wqg = Wqg; ma.Wkv1 = Wkv1; ma.Wkv2 = Wkv2; ma.Wk1l = Wk1l; ma.Wk2l = Wk2l;
    ma.q_b = q_b; ma.k1_b = k1_b; ma.k2_b = k2_b; ma.v1_b = v1_b; ma.v2_b = v2_b;
    ma.g1_b = g1_b; ma.g2_b = g2_b;
    ma.K1f = K1f; ma.K2f = K2f; ma.V1b = V1b; ma.V2b = V2b;
    ma.Qb = Qb; ma.G1b = G1b; ma.G2b = G2b;
    mega_gemm<<<1408, 256, 0, stream>>>(ma);

    // 3) fused prep (K norms+cast+gram consts, Q norms, V transpose)
    prep_kernel<<<26624, 256, 0, stream>>>(K1f, K2f, K1b, K2b, vv, aa, va2, gg,
                                           Qb, ll, V1b, V2b, V1t, V2t);

    // 4) fused scores+softmax (single pass, register P', writes bf16 P)
    attn_fused<<<512, 256, 0, stream>>>(Qb, K1b, K2b, ll, vv, aa, va2, gg, attn);

    // 5) PV + gating, plus head-average path (flat grid)
    pv_gate_kernel<<<2304, 256, 0, stream>>>(attn, V1t, V2t, G1b, G2b, tmpb,
                                             out + (size_t)LQ * NB * EDIM);

    // 6) output projection
    gemm_o64<<<dim3(8, 32), 256, 0, stream>>>(tmpb, Wo, o_b, out);
}

// Round 4
// 361.147 us; speedup vs baseline: 1.5619x; 1.5619x over previous
//
#include <hip/hip_runtime.h>
#include <cstddef>
#include <cstdint>

typedef unsigned short ushort_t;
typedef unsigned int uint_t;
typedef __attribute__((ext_vector_type(8))) short short8;
typedef __attribute__((ext_vector_type(4))) float f32x4;

#define EDIM 1024
#define NHEAD 16
#define HDIM 64
#define NB 4
#define LQ 512
#define SK 1024
#define BHD 64

__device__ __forceinline__ ushort_t f2b(float f) {
    uint_t u = __float_as_uint(f);
    return (ushort_t)((u + 0x7fffu + ((u >> 16) & 1u)) >> 16);
}
__device__ __forceinline__ float b2f(ushort_t b) {
    return __uint_as_float(((uint_t)b) << 16);
}

__device__ __forceinline__ void gload_lds16(const void* g, void* l) {
    __builtin_amdgcn_global_load_lds((const __attribute__((address_space(1))) void*)g,
                                     (__attribute__((address_space(3))) void*)l, 16, 0, 0);
}

// ============ mega projection GEMM: all 5 jobs in one balanced launch ======
struct MegaArgs {
    const ushort_t *qx, *m1h, *m1l, *m2h, *m2l;
    const ushort_t *Wqg, *Wkv1, *Wkv2, *Wk1l, *Wk2l;
    const float *q_b, *k1_b, *k2_b, *v1_b, *v2_b, *g1_b, *g2_b;
    float *K1f, *K2f;
    ushort_t *V1b, *V2b, *Qb, *G1b, *G2b;
};

__global__ __launch_bounds__(256, 2)
void mega_gemm(MegaArgs a)
{
    __shared__ ushort_t As[128 * 64];
    __shared__ ushort_t Bs[128 * 64];
    const int tid = threadIdx.x;
    const int wave = tid >> 6, lane = tid & 63;
    const int ln = lane & 15, lq = lane >> 4;
    const int wm = wave & 1, wn = wave >> 1;
    const int mrl = lane >> 3;               // row within each 8-row staging group
    const int lswz = (lane & 7) ^ mrl;       // logical slot this lane stages

    const int id = blockIdx.x;
    f32x4 zero = {0.f, 0.f, 0.f, 0.f};

    if (id < 512) {
        // ===== merged split-precision K path: 3 products per 32-k step =====
        const int kind = id >> 8;
        const int t = id & 255;
        const int u = t >> 3;
        const int col0 = (u >> 2) * 128;                 // 8 col-panels
        const int row0 = ((t & 7) * 4 + (u & 3)) * 128;  // XCD owns 4-row stripe
        const ushort_t* Ah  = kind ? a.m2h : a.m1h;
        const ushort_t* Alo = kind ? a.m2l : a.m1l;
        const ushort_t* Bh  = kind ? a.Wkv2 : a.Wkv1;
        const ushort_t* Blo = kind ? a.Wk2l : a.Wk1l;
        const float* bias = kind ? a.k2_b : a.k1_b;

        f32x4 acc[4][4];
#pragma unroll
        for (int i = 0; i < 4; ++i)
#pragma unroll
            for (int j = 0; j < 4; ++j) acc[i][j] = zero;

        const int ksub = (lswz & 3) * 8;                 // k offset within 32-chunk
        const ushort_t* Asrc = (lswz & 4) ? Alo : Ah;    // per-lane hi/lo select
        const ushort_t* Bsrc = (lswz & 4) ? Blo : Bh;

        for (int kk = 0; kk < 1024; kk += 32) {
            __syncthreads();
#pragma unroll
            for (int j = 0; j < 4; ++j) {
                const int mr = (wave * 4 + j) * 8 + mrl;
                gload_lds16(Asrc + (size_t)(row0 + mr) * 1024 + kk + ksub,
                            (void*)(As + (wave * 4 + j) * 512));
                gload_lds16(Bsrc + (size_t)(col0 + mr) * 1024 + kk + ksub,
                            (void*)(Bs + (wave * 4 + j) * 512));
            }
            __syncthreads();
            short8 ah[4], alv[4], bh[4], blv[4];
#pragma unroll
            for (int i = 0; i < 4; ++i) {
                const int ml = wm * 64 + i * 16 + ln;
                const int pa = (lq ^ (ml & 7)) * 8;      // physical hi slot
                ah[i]  = *(const short8*)(As + ml * 64 + pa);
                alv[i] = *(const short8*)(As + ml * 64 + (pa ^ 32)); // lo = hi^4 slots
                const int nl = wn * 64 + i * 16 + ln;
                const int pb = (lq ^ (nl & 7)) * 8;
                bh[i]  = *(const short8*)(Bs + nl * 64 + pb);
                blv[i] = *(const short8*)(Bs + nl * 64 + (pb ^ 32));
            }
#pragma unroll
            for (int i = 0; i < 4; ++i)
#pragma unroll
                for (int j = 0; j < 4; ++j)
                    acc[i][j] = __builtin_amdgcn_mfma_f32_16x16x32_bf16(ah[i], bh[j], acc[i][j], 0, 0, 0);
#pragma unroll
            for (int i = 0; i < 4; ++i)
#pragma unroll
                for (int j = 0; j < 4; ++j)
                    acc[i][j] = __builtin_amdgcn_mfma_f32_16x16x32_bf16(ah[i], blv[j], acc[i][j], 0, 0, 0);
#pragma unroll
            for (int i = 0; i < 4; ++i)
#pragma unroll
                for (int j = 0; j < 4; ++j)
                    acc[i][j] = __builtin_amdgcn_mfma_f32_16x16x32_bf16(alv[i], bh[j], acc[i][j], 0, 0, 0);
        }

        float* Y = kind ? a.K2f : a.K1f;
#pragma unroll
        for (int i = 0; i < 4; ++i) {
#pragma unroll
            for (int r = 0; r < 4; ++r) {
                const int row = row0 + wm * 64 + i * 16 + lq * 4 + r;
#pragma unroll
                for (int j = 0; j < 4; ++j) {
                    const int col = col0 + wn * 64 + j * 16 + ln;
                    const float v = acc[i][j][r] + bias[col];
                    const int s = row >> 2, b = row & 3, h = col >> 6, d = col & 63;
                    Y[(((size_t)(b * 16 + h)) * 1024 + s) * 64 + d] = v;
                }
            }
        }
        return;
    }

    // ===================== V / QG single-pass path =====================
    int kind, row0, col0;
    const ushort_t *A, *B;
    const float* bias;
    if (id < 1024) {
        int t = id - 512; kind = 2 + (t >> 8); t &= 255;
        const int u = t >> 3;
        col0 = (u >> 2) * 128;
        row0 = ((t & 7) * 4 + (u & 3)) * 128;           // XCD row-stripe
        A = (kind == 2) ? a.m1h : a.m2h;
        B = ((kind == 2) ? a.Wkv1 : a.Wkv2) + (size_t)1024 * 1024;
        bias = (kind == 2) ? a.v1_b : a.v2_b;
    } else {
        const int t = id - 1024; kind = 4;
        const int u = t >> 3;
        const int c = (t & 7) * 3 + (u >> 4);           // XCD owns 3 col-panels
        const int rr = u & 15;
        col0 = c * 128; row0 = rr * 128;
        A = a.qx; B = a.Wqg;
        const int seg = c >> 3;
        bias = (seg == 0) ? a.q_b : ((seg == 1) ? a.g1_b : a.g2_b);
    }

    f32x4 acc[4][4];
#pragma unroll
    for (int i = 0; i < 4; ++i)
#pragma unroll
        for (int j = 0; j < 4; ++j) acc[i][j] = zero;

    for (int kk = 0; kk < 1024; kk += 64) {
        __syncthreads();
#pragma unroll
        for (int j = 0; j < 4; ++j) {
            const int mr = (wave * 4 + j) * 8 + mrl;
            gload_lds16(A + (size_t)(row0 + mr) * 1024 + kk + lswz * 8,
                        (void*)(As + (wave * 4 + j) * 512));
            gload_lds16(B + (size_t)(col0 + mr) * 1024 + kk + lswz * 8,
                        (void*)(Bs + (wave * 4 + j) * 512));
        }
        __syncthreads();
#pragma unroll
        for (int sub = 0; sub < 2; ++sub) {
            short8 af[4], bfv[4];
#pragma unroll
            for (int i = 0; i < 4; ++i) {
                const int ml = wm * 64 + i * 16 + ln;
                af[i] = *(const short8*)(As + ml * 64 + (((sub * 4 + lq) ^ (ml & 7)) * 8));
                const int nl = wn * 64 + i * 16 + ln;
                bfv[i] = *(const short8*)(Bs + nl * 64 + (((sub * 4 + lq) ^ (nl & 7)) * 8));
            }
#pragma unroll
            for (int i = 0; i < 4; ++i)
#pragma unroll
                for (int j = 0; j < 4; ++j)
                    acc[i][j] = __builtin_amdgcn_mfma_f32_16x16x32_bf16(af[i], bfv[j], acc[i][j], 0, 0, 0);
        }
    }

#pragma unroll
    for (int i = 0; i < 4; ++i) {
#pragma unroll
        for (int r = 0; r < 4; ++r) {
            const int row = row0 + wm * 64 + i * 16 + lq * 4 + r;
#pragma unroll
            for (int j = 0; j < 4; ++j) {
                const int col = col0 + wn * 64 + j * 16 + ln;
                const int lc = col & 1023;
                float v = acc[i][j][r] + bias[lc];
                if (kind <= 3) {            // V bf16 head-split
                    const int s = row >> 2, b = row & 3, h = lc >> 6, d = lc & 63;
                    ushort_t* Y = (kind == 2) ? a.V1b : a.V2b;
                    Y[(((size_t)(b * 16 + h)) * 1024 + s) * 64 + d] = f2b(v);
                } else {
                    const int seg = col >> 10;
                    if (seg == 0) {         // Q bf16 head-split (L=512), *scale
                        v *= 0.125f;
                        const int s = row >> 2, b = row & 3, h = lc >> 6, d = lc & 63;
                        a.Qb[(((size_t)(b * 16 + h)) * 512 + s) * 64 + d] = f2b(v);
                    } else {                // gates bf16 sigmoid flat
                        v = 1.0f / (1.0f + __expf(-v));
                        ushort_t* Y = (seg == 1) ? a.G1b : a.G2b;
                        Y[(size_t)row * 1024 + lc] = f2b(v);
                    }
                }
            }
        }
    }
}

// =============== fused input/weight casts (one launch) ===============
struct CastArgs {
    const float* q; const float* m1; const float* m2;
    ushort_t* qx; ushort_t* m1h; ushort_t* m1l; ushort_t* m2h; ushort_t* m2l;
    const float* wsrc[8];
    ushort_t* whi[8];
    ushort_t* wlo[8];
};

__global__ __launch_bounds__(256)
void casts_kernel(CastArgs a)
{
    __shared__ float T[64][65];
    const int id = blockIdx.x;
    const int tid = threadIdx.x;
    if (id < 1024) {                       // query cast
        const size_t i = ((size_t)id * 256 + tid) * 8;
        float4 x = *(const float4*)(a.q + i);
        float4 y = *(const float4*)(a.q + i + 4);
        ushort_t o[8] = {f2b(x.x), f2b(x.y), f2b(x.z), f2b(x.w), f2b(y.x), f2b(y.y), f2b(y.z), f2b(y.w)};
        *(uint4*)( (void*)(a.qx + i) ) = *(const uint4*)o;
    } else if (id < 5120) {                // mod hi/lo split casts
        const int t = id - 1024;
        const int which = t >> 11;
        const float* x = which ? a.m2 : a.m1;
        ushort_t* yh = which ? a.m2h : a.m1h;
        ushort_t* yl = which ? a.m2l : a.m1l;
        const size_t i = ((size_t)(t & 2047) * 256 + tid) * 8;
        float v[8];
        *(float4*)v = *(const float4*)(x + i);
        *(float4*)(v + 4) = *(const float4*)(x + i + 4);
        ushort_t oh[8], ol[8];
#pragma unroll
        for (int k = 0; k < 8; ++k) {
            oh[k] = f2b(v[k]);
            ol[k] = f2b(v[k] - b2f(oh[k]));
        }
        *(uint4*)( (void*)(yh + i) ) = *(const uint4*)oh;
        *(uint4*)( (void*)(yl + i) ) = *(const uint4*)ol;
    } else {                               // weight transpose+cast
        const int t = id - 5120;
        const int z = t >> 8, x = t & 15, y = (t >> 4) & 15;
        const float* W = a.wsrc[z];
        ushort_t* Th = a.whi[z];
        ushort_t* Tl = a.wlo[z];
        const int k0 = x * 64, n0 = y * 64;
        const int r = tid >> 2, cg = (tid & 3) * 16;
#pragma unroll
        for (int u = 0; u < 4; ++u) {
            float4 v = *(const float4*)(W + (size_t)(k0 + r) * 1024 + n0 + cg + u * 4);
            T[r][cg + u * 4 + 0] = v.x; T[r][cg + u * 4 + 1] = v.y;
            T[r][cg + u * 4 + 2] = v.z; T[r][cg + u * 4 + 3] = v.w;
        }
        __syncthreads();
        ushort_t oh[16], ol[16];
#pragma unroll
        for (int u = 0; u < 16; ++u) {
            float v = T[cg + u][r];
            oh[u] = f2b(v);
            ol[u] = f2b(v - b2f(oh[u]));
        }
        ushort_t* dh = Th + (size_t)(n0 + r) * 1024 + k0 + cg;
        *(uint4*)( (void*)dh ) = *(const uint4*)oh;
        *(uint4*)( (void*)(dh + 8) ) = *(const uint4*)(oh + 8);
        if (Tl) {
            ushort_t* dl = Tl + (size_t)(n0 + r) * 1024 + k0 + cg;
            *(uint4*)( (void*)dl ) = *(const uint4*)ol;
            *(uint4*)( (void*)(dl + 8) ) = *(const uint4*)(ol + 8);
        }
    }
}

// ====== fused prep: K norms+cast, Q norms, V transpose (one launch) ======
__global__ __launch_bounds__(256)
void prep_kernel(const float* __restrict__ K1f, const float* __restrict__ K2f,
                 ushort_t* __restrict__ K1b, ushort_t* __restrict__ K2b,
                 float* __restrict__ vv, float* __restrict__ aa,
                 float* __restrict__ va2, float* __restrict__ gg,
                 const ushort_t* __restrict__ Qb, float* __restrict__ ll,
                 const ushort_t* __restrict__ V1b, const ushort_t* __restrict__ V2b,
                 ushort_t* __restrict__ V1t, ushort_t* __restrict__ V2t)
{
    __shared__ float T[64][65];
    const int id = blockIdx.x;
    const int tid = threadIdx.x;
    const int wave = tid >> 6, lane = tid & 63;
    if (id < 16384) {                      // K norms (fp32) + bf16 cast
        const int row = id * 4 + wave;
        const float x1 = K1f[(size_t)row * 64 + lane];
        const float x2 = K2f[(size_t)row * 64 + lane];
        K1b[(size_t)row * 64 + lane] = f2b(x1);
        K2b[(size_t)row * 64 + lane] = f2b(x2);
        float s1 = x1 * x1, s2 = x2 * x2, s3 = x1 * x2;
#pragma unroll
        for (int o = 1; o < 64; o <<= 1) {
            s1 += __shfl_xor(s1, o);
            s2 += __shfl_xor(s2, o);
            s3 += __shfl_xor(s3, o);
        }
        if (lane == 0) {
            vv[row] = s1; aa[row] = s2;
            va2[row] = 2.0f * s3;
            gg[row] = s1 * s2 - s3 * s3;
        }
    } else if (id < 24576) {               // Q norms
        const int row = (id - 16384) * 4 + wave;
        const float x = b2f(Qb[(size_t)row * 64 + lane]);
        float s = x * x;
#pragma unroll
        for (int o = 1; o < 64; o <<= 1) s += __shfl_xor(s, o);
        if (lane == 0) ll[row] = s;
    } else {                               // V transpose
        const int t = id - 24576;
        const int z = t >> 10, bh = (t >> 4) & 63, s0 = (t & 15) * 64;
        const ushort_t* S = z ? V2b : V1b;
        ushort_t* D = z ? V2t : V1t;
        const int r = tid >> 2, cg = (tid & 3) * 16;
        ushort_t buf[16];
        const ushort_t* sp = S + ((size_t)bh * 1024 + s0 + r) * 64 + cg;
        *(uint4*)buf = *(const uint4*)sp;
        *(uint4*)(buf + 8) = *(const uint4*)(sp + 8);
#pragma unroll
        for (int u = 0; u < 16; ++u) T[r][cg + u] = b2f(buf[u]);
        __syncthreads();
        ushort_t o[16];
#pragma unroll
        for (int u = 0; u < 16; ++u) o[u] = f2b(T[cg + u][r]);
        ushort_t* d = D + ((size_t)bh * 64 + r) * 1024 + s0 + cg;
        *(uint4*)( (void*)d ) = *(const uint4*)o;
        *(uint4*)( (void*)(d + 8) ) = *(const uint4*)(o + 8);
    }
}

// ====== fused scores + softmax: single pass, streamed unnormalized P' ======
// Block = (bh, 64 q-rows) x full S=1024. Per 128-col s-tile: MFMA QK, det,
// tile max mn_t; write P' = exp(lgt - mn_t) bf16 straight to attn (64 MB,
// same bytes the old pass-2 wrote). Keep only mt[8][4] in regs. After the
// loop, store per-(row,tile) correction C[bh][l][t] = exp(mt - m_fin) * inv
// (1 MB). PV/avg apply C downstream -> no recompute pass, no spills.
__global__ __launch_bounds__(256, 2)
void attn_fused(const ushort_t* __restrict__ Qb, const ushort_t* __restrict__ K1b,
                const ushort_t* __restrict__ K2b, const float* __restrict__ ll,
                const float* __restrict__ vv, const float* __restrict__ aa,
                const float* __restrict__ va2, const float* __restrict__ gg,
                ushort_t* __restrict__ attn, float* __restrict__ C)
{
    __shared__ ushort_t Qs[64 * 64];
    __shared__ ushort_t K1s[128 * 64];
    __shared__ ushort_t K2s[128 * 64];
    __shared__ float vvS[1024], aaS[1024], vaS[1024], ggS[1024], llS[64];
    const int tid = threadIdx.x;
    const int wave = tid >> 6, lane = tid & 63;
    const int ln = lane & 15, lq = lane >> 4;
    const int mrl = lane >> 3;
    const int cswz = (lane & 7) ^ mrl;
    const float L2E = 1.44269504f;

    const int id = blockIdx.x;
    // bijective XCD map: XCD k owns bh = k*8 .. k*8+7 (all 8 l-blocks local)
    const int bh = (id & 7) * 8 + ((id >> 3) & 7);
    const int l0 = (id >> 6) * 64;

    for (int i = tid; i < 1024; i += 256) {
        vvS[i] = vv[(size_t)bh * 1024 + i];
        aaS[i] = aa[(size_t)bh * 1024 + i];
        vaS[i] = va2[(size_t)bh * 1024 + i];
        ggS[i] = gg[(size_t)bh * 1024 + i];
    }
    if (tid < 64) llS[tid] = ll[(size_t)bh * 512 + l0 + tid];
#pragma unroll
    for (int j = 0; j < 2; ++j) {          // stage Q once (64x64)
        const int mr = (wave * 2 + j) * 8 + mrl;
        gload_lds16(Qb + ((size_t)bh * 512 + l0 + mr) * 64 + cswz * 8,
                    (void*)(Qs + (wave * 2 + j) * 512));
    }

    const int ml = wave * 16 + ln;         // this wave's A-frag row base
    const size_t rb = (size_t)bh * 512 + l0 + wave * 16 + lq * 4;

    float m_run[4], s_run[4];
#pragma unroll
    for (int r = 0; r < 4; ++r) { m_run[r] = -3.0e38f; s_run[r] = 0.f; }
    float mt[8][4];                        // running max at each tile

#pragma unroll
    for (int t = 0; t < 8; ++t) {
        const int s0 = t * 128;
        __syncthreads();
#pragma unroll
        for (int j = 0; j < 4; ++j) {
            const int mr = (wave * 4 + j) * 8 + mrl;
            gload_lds16(K1b + ((size_t)bh * 1024 + s0 + mr) * 64 + cswz * 8,
                        (void*)(K1s + (wave * 4 + j) * 512));
            gload_lds16(K2b + ((size_t)bh * 1024 + s0 + mr) * 64 + cswz * 8,
                        (void*)(K2s + (wave * 4 + j) * 512));
        }
        __syncthreads();
        f32x4 zero = {0.f, 0.f, 0.f, 0.f};
        f32x4 lv[8], la[8];
#pragma unroll
        for (int j = 0; j < 8; ++j) { lv[j] = zero; la[j] = zero; }
#pragma unroll
        for (int sub = 0; sub < 2; ++sub) {
            const short8 qf = *(const short8*)(Qs + ml * 64 + (((sub * 4 + lq) ^ (ml & 7)) * 8));
#pragma unroll
            for (int j = 0; j < 8; ++j) {
                const int nl = j * 16 + ln;
                const short8 k1f = *(const short8*)(K1s + nl * 64 + (((sub * 4 + lq) ^ (nl & 7)) * 8));
                const short8 k2f = *(const short8*)(K2s + nl * 64 + (((sub * 4 + lq) ^ (nl & 7)) * 8));
                lv[j] = __builtin_amdgcn_mfma_f32_16x16x32_bf16(qf, k1f, lv[j], 0, 0, 0);
                la[j] = __builtin_amdgcn_mfma_f32_16x16x32_bf16(qf, k2f, la[j], 0, 0, 0);
            }
        }
        float lgt[8][4];
#pragma unroll
        for (int j = 0; j < 8; ++j) {
            const int c = s0 + j * 16 + ln;
            const float VV = vvS[c], AA = aaS[c], VA2 = vaS[c], GB = ggS[c];
#pragma unroll
            for (int r = 0; r < 4; ++r) {
                const float LL = llS[wave * 16 + lq * 4 + r];
                const float LV = lv[j][r], LA = la[j][r];
                float det = LL * GB;
                det = fmaf(-AA, LV * LV, det);
                det = fmaf(VA2, LV * LA, det);
                det = fmaf(-VV, LA * LA, det);
                det = fmaxf(det, 1e-8f);
                lgt[j][r] = (LV + LA) - 1.5f * sqrtf(det);
            }
        }
        // tile max across the 16 lanes sharing this row group
        float tmax[4];
#pragma unroll
        for (int r = 0; r < 4; ++r) tmax[r] = lgt[0][r];
#pragma unroll
        for (int j = 1; j < 8; ++j)
#pragma unroll
            for (int r = 0; r < 4; ++r) tmax[r] = fmaxf(tmax[r], lgt[j][r]);
#pragma unroll
        for (int r = 0; r < 4; ++r) {
#pragma unroll
            for (int o = 1; o < 16; o <<= 1) tmax[r] = fmaxf(tmax[r], __shfl_xor(tmax[r], o));
        }
        float mn[4], nm[4], ps[4];
#pragma unroll
        for (int r = 0; r < 4; ++r) {
            mn[r] = fmaxf(m_run[r], tmax[r]);
            nm[r] = -mn[r] * L2E;
            ps[r] = 0.f;
        }
#pragma unroll
        for (int j = 0; j < 8; ++j) {
            const int col = s0 + j * 16 + ln;
            float p[4];
#pragma unroll
            for (int r = 0; r < 4; ++r) {
                p[r] = exp2f(fmaf(lgt[j][r], L2E, nm[r]));
                ps[r] += p[r];
            }
            attn[(rb + 0) * 1024 + col] = f2b(p[0]);
            attn[(rb + 1) * 1024 + col] = f2b(p[1]);
            attn[(rb + 2) * 1024 + col] = f2b(p[2]);
            attn[(rb + 3) * 1024 + col] = f2b(p[3]);
        }
#pragma unroll
        for (int r = 0; r < 4; ++r) {
            s_run[r] = s_run[r] * __expf(m_run[r] - mn[r]) + ps[r];
            m_run[r] = mn[r];
            mt[t][r] = mn[r];
        }
    }

    float inv[4];
#pragma unroll
    for (int r = 0; r < 4; ++r) {
        float s = s_run[r];
#pragma unroll
        for (int o = 1; o < 16; o <<= 1) s += __shfl_xor(s, o);
        inv[r] = 1.0f / s;
    }

    // store per-(row,tile) corrections (identical across the 16 ln lanes)
    if (ln == 0) {
#pragma unroll
        for (int t = 0; t < 8; ++t) {
#pragma unroll
            for (int r = 0; r < 4; ++r)
                C[(rb + r) * 8 + t] = __expf(mt[t][r] - m_run[r]) * inv[r];
        }
    }
}

// ====== PV (v1,v2) + gating -> tmp bf16 [t][E]; plus head-avg path ========
// P in attn is unnormalized per-tile (scale C[bh][l][t]); PV accumulates each
// 128-wide tile into tacc, then acc += c_t * tacc (deferred rescale, fp32).
__global__ __launch_bounds__(256, 2)
void pv_gate_kernel(const ushort_t* __restrict__ attn, const ushort_t* __restrict__ V1t,
                    const ushort_t* __restrict__ V2t, const ushort_t* __restrict__ G1,
                    const ushort_t* __restrict__ G2, const float* __restrict__ C,
                    ushort_t* __restrict__ tmpb, float* __restrict__ avg)
{
    __shared__ ushort_t Ps[128 * 64];
    __shared__ ushort_t V1s[64 * 64];
    __shared__ ushort_t V2s[64 * 64];
    const int tid = threadIdx.x;

    if (blockIdx.x >= 256) {               // ---- head-average path ----
        const int t = blockIdx.x - 256;    // 0..2047 = 4 b x 512 l
        const int b = t >> 9, l = t & 511;
        const int c0 = tid * 4;
        const int tt = tid >> 5;           // tile index of these 4 cols
        float s0_ = 0.f, s1_ = 0.f, s2_ = 0.f, s3_ = 0.f;
#pragma unroll
        for (int h = 0; h < 16; ++h) {
            const size_t row = ((size_t)(b * 16 + h)) * 512 + l;
            const float ch = C[row * 8 + tt];
            const ushort_t* p = attn + row * 1024 + c0;
            ushort_t u[4];
            *(uint2*)u = *(const uint2*)p;
            s0_ = fmaf(b2f(u[0]), ch, s0_); s1_ = fmaf(b2f(u[1]), ch, s1_);
            s2_ = fmaf(b2f(u[2]), ch, s2_); s3_ = fmaf(b2f(u[3]), ch, s3_);
        }
        float4 o = {s0_ * 0.0625f, s1_ * 0.0625f, s2_ * 0.0625f, s3_ * 0.0625f};
        *(float4*)(avg + ((size_t)(b * 512 + l)) * 1024 + c0) = o;
        return;
    }

    const int wave = tid >> 6, lane = tid & 63;
    const int ln = lane & 15, lq = lane >> 4;
    const int bh = blockIdx.x >> 2;
    const int l0 = (blockIdx.x & 3) * 128;
    const int cswz = (lane & 7) ^ ((lane >> 3) & 7);
    const int mrl = lane >> 3;
    const int bq = bh >> 4, h = bh & 15;

    f32x4 zero = {0.f, 0.f, 0.f, 0.f};
    f32x4 acc1[2][4], acc2[2][4], tacc1[2][4], tacc2[2][4];
#pragma unroll
    for (int i = 0; i < 2; ++i)
#pragma unroll
        for (int j = 0; j < 4; ++j) {
            acc1[i][j] = zero; acc2[i][j] = zero;
            tacc1[i][j] = zero; tacc2[i][j] = zero;
        }

    for (int s0 = 0; s0 < 1024; s0 += 64) {
        __syncthreads();
#pragma unroll
        for (int j = 0; j < 4; ++j) {
            const int mr = (wave * 4 + j) * 8 + mrl;
            gload_lds16(attn + ((size_t)bh * 512 + l0 + mr) * 1024 + s0 + cswz * 8,
                        (void*)(Ps + (wave * 4 + j) * 512));
        }
#pragma unroll
        for (int j = 0; j < 2; ++j) {
            const int mv = (wave * 2 + j) * 8 + mrl;
            gload_lds16(V1t + ((size_t)bh * 64 + mv) * 1024 + s0 + cswz * 8,
                        (void*)(V1s + (wave * 2 + j) * 512));
            gload_lds16(V2t + ((size_t)bh * 64 + mv) * 1024 + s0 + cswz * 8,
                        (void*)(V2s + (wave * 2 + j) * 512));
        }
        __syncthreads();
#pragma unroll
        for (int sub = 0; sub < 2; ++sub) {
            short8 af[2], b1f[4], b2f_[4];
#pragma unroll
            for (int i = 0; i < 2; ++i) {
                const int ml = wave * 32 + i * 16 + ln;
                af[i] = *(const short8*)(Ps + ml * 64 + (((sub * 4 + lq) ^ (ml & 7)) * 8));
            }
#pragma unroll
            for (int j = 0; j < 4; ++j) {
                const int nl = j * 16 + ln;
                b1f[j] = *(const short8*)(V1s + nl * 64 + (((sub * 4 + lq) ^ (nl & 7)) * 8));
                b2f_[j] = *(const short8*)(V2s + nl * 64 + (((sub * 4 + lq) ^ (nl & 7)) * 8));
            }
#pragma unroll
            for (int i = 0; i < 2; ++i)
#pragma unroll
                for (int j = 0; j < 4; ++j) {
                    tacc1[i][j] = __builtin_amdgcn_mfma_f32_16x16x32_bf16(af[i], b1f[j], tacc1[i][j], 0, 0, 0);
                    tacc2[i][j] = __builtin_amdgcn_mfma_f32_16x16x32_bf16(af[i], b2f_[j], tacc2[i][j], 0, 0, 0);
                }
        }
        if (s0 & 64) {                     // end of a 128-wide tile: fold in
            const int tt = s0 >> 7;
#pragma unroll
            for (int i = 0; i < 2; ++i) {
#pragma unroll
                for (int r = 0; r < 4; ++r) {
                    const int l = l0 + wave * 32 + i * 16 + lq * 4 + r;
                    const float c = C[((size_t)bh * 512 + l) * 8 + tt];
#pragma unroll
                    for (int j = 0; j < 4; ++j) {
                        acc1[i][j][r] = fmaf(c, tacc1[i][j][r], acc1[i][j][r]);
                        acc2[i][j][r] = fmaf(c, tacc2[i][j][r], acc2[i][j][r]);
                    }
                }
            }
#pragma unroll
            for (int i = 0; i < 2; ++i)
#pragma unroll
                for (int j = 0; j < 4; ++j) { tacc1[i][j] = zero; tacc2[i][j] = zero; }
        }
    }

#pragma unroll
    for (int i = 0; i < 2; ++i) {
#pragma unroll
        for (int r = 0; r < 4; ++r) {
            const int l = l0 + wave * 32 + i * 16 + lq * 4 + r;
#pragma unroll
            for (int j = 0; j < 4; ++j) {
                const int d = j * 16 + ln;
                const size_t addr = ((size_t)l * 4 + bq) * 1024 + h * 64 + d;
                const float v = 0.5f * (acc1[i][j][r] * b2f(G1[addr]) + acc2[i][j][r] * b2f(G2[addr]));
                tmpb[addr] = f2b(v);
            }
        }
    }
}

// ============ o-proj: 64x128 tiles, 256 blocks (fixed coverage) ============
__global__ __launch_bounds__(256, 2)
void gemm_o64(const ushort_t* __restrict__ A, const ushort_t* __restrict__ B,
              const float* __restrict__ bias, float* __restrict__ Y)
{
    __shared__ ushort_t As[64 * 64];
    __shared__ ushort_t Bs[128 * 64];
    const int tid = threadIdx.x;
    const int wave = tid >> 6, lane = tid & 63;
    const int ln = lane & 15, lq = lane >> 4;
    const int row0 = blockIdx.y * 64, col0 = blockIdx.x * 128;
    const int wm = wave & 1, wn = wave >> 1;
    const int cswz = (lane & 7) ^ ((lane >> 3) & 7);
    const int mrl = lane >> 3;

    f32x4 zero = {0.f, 0.f, 0.f, 0.f};
    f32x4 acc[2][4];
#pragma unroll
    for (int i = 0; i < 2; ++i)
#pragma unroll
        for (int j = 0; j < 4; ++j) acc[i][j] = zero;

    for (int kk = 0; kk < 1024; kk += 64) {
        __syncthreads();
#pragma unroll
        for (int j = 0; j < 2; ++j) {       // A: 64 rows
            const int mr = (wave * 2 + j) * 8 + mrl;
            gload_lds16(A + (size_t)(row0 + mr) * 1024 + kk + cswz * 8,
                        (void*)(As + (wave * 2 + j) * 512));
        }
#pragma unroll
        for (int j = 0; j < 4; ++j) {       // B: 128 rows
            const int mr = (wave * 4 + j) * 8 + mrl;
            gload_lds16(B + (size_t)(col0 + mr) * 1024 + kk + cswz * 8,
                        (void*)(Bs + (wave * 4 + j) * 512));
        }
        __syncthreads();
#pragma unroll
        for (int sub = 0; sub < 2; ++sub) {
            short8 af[2], bfv[4];
#pragma unroll
            for (int i = 0; i < 2; ++i) {
                const int ml = wm * 32 + i * 16 + ln;
                af[i] = *(const short8*)(As + ml * 64 + (((sub * 4 + lq) ^ (ml & 7)) * 8));
            }
#pragma unroll
            for (int j = 0; j < 4; ++j) {
                const int nl = wn * 64 + j * 16 + ln;
                bfv[j] = *(const short8*)(Bs + nl * 64 + (((sub * 4 + lq) ^ (nl & 7)) * 8));
            }
#pragma unroll
            for (int i = 0; i < 2; ++i)
#pragma unroll
                for (int j = 0; j < 4; ++j)
                    acc[i][j] = __builtin_amdgcn_mfma_f32_16x16x32_bf16(af[i], bfv[j], acc[i][j], 0, 0, 0);
        }
    }

#pragma unroll
    for (int i = 0; i < 2; ++i) {
#pragma unroll
        for (int r = 0; r < 4; ++r) {
            const int row = row0 + wm * 32 + i * 16 + lq * 4 + r;
#pragma unroll
            for (int j = 0; j < 4; ++j) {
                const int col = col0 + wn * 64 + j * 16 + ln;
                Y[(size_t)row * 1024 + col] = acc[i][j][r] + bias[col];
            }
        }
    }
}

// ============================ launch ============================
extern "C" void kernel_launch(void* const* d_in, const int* in_sizes, int n_in,
                              void* d_out, int out_size, void* d_ws, size_t ws_size,
                              hipStream_t stream)
{
    const float* query = (const float*)d_in[0];
    const float* mod1  = (const float*)d_in[1];
    const float* mod2  = (const float*)d_in[2];
    const float* q_w  = (const float*)d_in[3];  const float* q_b  = (const float*)d_in[4];
    const float* k1_w = (const float*)d_in[5];  const float* k1_b = (const float*)d_in[6];
    const float* k2_w = (const float*)d_in[7];  const float* k2_b = (const float*)d_in[8];
    const float* v1_w = (const float*)d_in[9];  const float* v1_b = (const float*)d_in[10];
    const float* v2_w = (const float*)d_in[11]; const float* v2_b = (const float*)d_in[12];
    const float* g1_w = (const float*)d_in[13]; const float* g1_b = (const float*)d_in[14];
    const float* g2_w = (const float*)d_in[15]; const float* g2_b = (const float*)d_in[16];
    const float* o_w  = (const float*)d_in[17]; const float* o_b  = (const float*)d_in[18];
    float* out = (float*)d_out;

    const size_t MB = 1u << 20;
    char* w = (char*)d_ws;
    // persistent region (0..78 MB)
    ushort_t* Wqg  = (ushort_t*)(w + 0 * MB);    // 6 MB [q|g1|g2]^T
    ushort_t* Wkv1 = (ushort_t*)(w + 6 * MB);    // 4 MB [k1|v1]^T
    ushort_t* Wkv2 = (ushort_t*)(w + 10 * MB);   // 4 MB [k2|v2]^T
    ushort_t* Wo   = (ushort_t*)(w + 14 * MB);   // 2 MB
    ushort_t* Wk1l = (ushort_t*)(w + 16 * MB);   // 2 MB
    ushort_t* Wk2l = (ushort_t*)(w + 18 * MB);   // 2 MB
    ushort_t* qx   = (ushort_t*)(w + 20 * MB);   // 4 MB; dead after mega-GEMM
    ushort_t* tmpb = qx;                         // reuse for gated PV output
    ushort_t* Qb   = (ushort_t*)(w + 24 * MB);   // 4 MB (full 64*512*64)
    ushort_t* K1b  = (ushort_t*)(w + 28 * MB);   // 8 MB
    ushort_t* K2b  = (ushort_t*)(w + 36 * MB);   // 8 MB
    ushort_t* V1t  = (ushort_t*)(w + 44 * MB);   // 8 MB
    ushort_t* V2t  = (ushort_t*)(w + 52 * MB);   // 8 MB
    ushort_t* G1b  = (ushort_t*)(w + 60 * MB);   // 4 MB bf16 gates
    ushort_t* G2b  = (ushort_t*)(w + 64 * MB);   // 4 MB
    float* ll  = (float*)(w + 68 * MB);                  // 128 KB
    float* vv  = (float*)(w + 68 * MB + 256 * 1024);     // 256 KB each slot
    float* aa  = (float*)(w + 68 * MB + 512 * 1024);
    float* va2 = (float*)(w + 68 * MB + 768 * 1024);
    float* gg  = (float*)(w + 68 * MB + 1024 * 1024);
    float* Cs  = (float*)(w + 70 * MB);          // 1 MB per-(row,tile) scales
    // transient region 78..158 MB; overlays all dead before attn_fused:
    ushort_t* attn = (ushort_t*)(w + 78 * MB);   // 64 MB bf16 [bh][512][1024]
    ushort_t* m1h = (ushort_t*)(w + 78 * MB);    // 8 MB  (dead after mega-GEMM)
    ushort_t* m2h = (ushort_t*)(w + 86 * MB);    // 8 MB
    ushort_t* m1l = (ushort_t*)(w + 94 * MB);    // 8 MB
    ushort_t* m2l = (ushort_t*)(w + 102 * MB);   // 8 MB
    float* K1f = (float*)(w + 110 * MB);         // 16 MB (dead after prep)
    float* K2f = (float*)(w + 126 * MB);         // 16 MB
    ushort_t* V1b = (ushort_t*)(w + 142 * MB);   // 8 MB (dead after prep)
    ushort_t* V2b = (ushort_t*)(w + 150 * MB);   // 8 MB

    // 1) fused casts
    CastArgs ca;
    ca.q = query; ca.m1 = mod1; ca.m2 = mod2;
    ca.qx = qx; ca.m1h = m1h; ca.m1l = m1l; ca.m2h = m2h; ca.m2l = m2l;
    const float* srcs[8] = {q_w, g1_w, g2_w, k1_w, v1_w, k2_w, v2_w, o_w};
    ushort_t* his[8] = {Wqg, Wqg + (size_t)1024 * 1024, Wqg + (size_t)2048 * 1024,
                        Wkv1, Wkv1 + (size_t)1024 * 1024, Wkv2, Wkv2 + (size_t)1024 * 1024, Wo};
    ushort_t* los[8] = {nullptr, nullptr, nullptr, Wk1l, nullptr, Wk2l, nullptr, nullptr};
    for (int i = 0; i < 8; ++i) { ca.wsrc[i] = srcs[i]; ca.whi[i] = his[i]; ca.wlo[i] = los[i]; }
    casts_kernel<<<7168, 256, 0, stream>>>(ca);

    // 2) all projections, one balanced launch
    MegaArgs ma;
    ma.qx = qx; ma.m1h = m1h; ma.m1l = m1l; ma.m2h = m2h; ma.m2l = m2l;
    ma.Wqg = Wqg; ma.Wkv1 = Wkv1; ma.Wkv2 = Wkv2; ma.Wk1l = Wk1l; ma.Wk2l = Wk2l;
    ma.q_b = q_b; ma.k1_b = k1_b; ma.k2_b = k2_b; ma.v1_b = v1_b; ma.v2_b = v2_b;
    ma.g1_b = g1_b; ma.g2_b = g2_b;
    ma.K1f = K1f; ma.K2f = K2f; ma.V1b = V1b; ma.V2b = V2b;
    ma.Qb = Qb; ma.G1b = G1b; ma.G2b = G2b;
    mega_gemm<<<1408, 256, 0, stream>>>(ma);

    // 3) fused prep (K norms+cast+gram consts, Q norms, V transpose)
    prep_kernel<<<26624, 256, 0, stream>>>(K1f, K2f, K1b, K2b, vv, aa, va2, gg,
                                           Qb, ll, V1b, V2b, V1t, V2t);

    // 4) fused scores+softmax (single pass, streams P' + C scales)
    attn_fused<<<512, 256, 0, stream>>>(Qb, K1b, K2b, ll, vv, aa, va2, gg, attn, Cs);

    // 5) PV + gating (deferred per-tile rescale), plus head-average path
    pv_gate_kernel<<<2304, 256, 0, stream>>>(attn, V1t, V2t, G1b, G2b, Cs, tmpb,
                                             out + (size_t)LQ * NB * EDIM);

    // 6) output projection
    gemm_o64<<<dim3(8, 32), 256, 0, stream>>>(tmpb, Wo, o_b, out);
}